// Round 2
// baseline (708.299 us; speedup 1.0000x reference)
//
#include <hip/hip_runtime.h>
#include <hip/hip_bf16.h>
#include <stdint.h>

// Problem constants
#define MM 8192   // B*S
#define NN 4096   // F_OUT
#define KK 4096   // F_IN
#define PP 512
#define QIN 8
#define QOUT 8

typedef __bf16 bf16x8 __attribute__((ext_vector_type(8)));
typedef float  f32x4  __attribute__((ext_vector_type(4)));

static __device__ __forceinline__ uint16_t f2bf(float f) {
    uint32_t x = __builtin_bit_cast(uint32_t, f);
    uint32_t r = (x + 0x7fffu + ((x >> 16) & 1u)) >> 16;  // RNE
    return (uint16_t)r;
}

// ---------------------------------------------------------------------------
// Kernel 1: materialize dense circulant weight as bf16, sign folded in.
// Wt[n][k] = bf16( w[o=n>>9][i=k>>9][(r-j)&511] ) * (sign_bits[k] ? -1 : +1)
// w is fp32 (tiny, 128 KB -> L2-resident); Wt is [N][K] row-major bf16.
// One thread produces 8 consecutive k (16 B write).
// ---------------------------------------------------------------------------
__global__ __launch_bounds__(256) void build_w(const float* __restrict__ w,
                                               const int* __restrict__ sign_bits,
                                               uint16_t* __restrict__ Wt) {
    int idx = blockIdx.x * 256 + threadIdx.x;   // 0 .. NN*512-1
    int n  = idx >> 9;            // output feature
    int k0 = (idx & 511) << 3;    // first of 8 input features
    int o = n >> 9;
    int r = n & 511;
    int i = k0 >> 9;              // same input block for all 8
    const float* wrow = w + (((size_t)o * QIN + i) << 9);

    uint16_t vals[8];
#pragma unroll
    for (int t = 0; t < 8; ++t) {
        int k = k0 + t;
        int j = k & 511;
        uint16_t wv = f2bf(wrow[(r - j) & 511]);
        vals[t] = sign_bits[k] ? (uint16_t)(wv ^ 0x8000u) : wv;  // exact +/-1
    }
    uint4 pk;
    __builtin_memcpy(&pk, vals, 16);
    *(uint4*)(Wt + (size_t)n * KK + k0) = pk;
}

// ---------------------------------------------------------------------------
// Kernel 2: C = gelu(A @ Wt^T + bias). A fp32 [M][K] (cast to bf16 while
// staging), Wt bf16 [N][K], bias fp32, out fp32 [M][N].
// 128x128 tile, BK=32, 256 threads (4 waves 2x2), 4x4 16x16x32 MFMA per wave.
// ---------------------------------------------------------------------------
__global__ __launch_bounds__(256) void gemm_bias_gelu(const float* __restrict__ A,
                                                      const uint16_t* __restrict__ Wt,
                                                      const float* __restrict__ bias,
                                                      float* __restrict__ out) {
    __shared__ uint16_t sA[128 * 32];
    __shared__ uint16_t sB[128 * 32];

    const int tid  = threadIdx.x;
    const int lane = tid & 63;
    const int wave = tid >> 6;
    const int wm   = wave & 1;        // wave row (M half)
    const int wn   = wave >> 1;       // wave col (N half)
    const int quad = lane >> 4;       // 0..3
    const int r16  = lane & 15;

    const int m0 = blockIdx.y * 128;
    const int n0 = blockIdx.x * 128;

    // staging: thread t handles rows (t>>2) and (t>>2)+64, col group (t&3)*8.
    const int srow = tid >> 2;
    const int scol = (tid & 3) * 8;

    const float*    gA0 = A  + (size_t)(m0 + srow)      * KK + scol;
    const float*    gA1 = A  + (size_t)(m0 + srow + 64) * KK + scol;
    const uint16_t* gB0 = Wt + (size_t)(n0 + srow)      * KK + scol;
    const uint16_t* gB1 = Wt + (size_t)(n0 + srow + 64) * KK + scol;

    uint16_t* wA0 = sA + srow * 32 + scol;
    uint16_t* wA1 = sA + (srow + 64) * 32 + scol;
    uint16_t* wB0 = sB + srow * 32 + scol;
    uint16_t* wB1 = sB + (srow + 64) * 32 + scol;

    // compute-side LDS bases (A frag: m=r16, k=quad*8+j; B frag: n=r16)
    const uint16_t* pA = sA + (size_t)(wm * 64 + r16) * 32 + quad * 8;
    const uint16_t* pB = sB + (size_t)(wn * 64 + r16) * 32 + quad * 8;

    f32x4 acc[4][4];
#pragma unroll
    for (int mi = 0; mi < 4; ++mi)
#pragma unroll
        for (int ni = 0; ni < 4; ++ni)
            acc[mi][ni] = (f32x4)(0.0f);

    for (int k0 = 0; k0 < KK; k0 += 32) {
        // A: 8 fp32 per row-chunk -> cvt to 8 bf16
        float4 af0 = *(const float4*)(gA0 + k0);
        float4 af1 = *(const float4*)(gA0 + k0 + 4);
        float4 af2 = *(const float4*)(gA1 + k0);
        float4 af3 = *(const float4*)(gA1 + k0 + 4);
        uint4  b0  = *(const uint4*)(gB0 + k0);
        uint4  b1  = *(const uint4*)(gB1 + k0);

        uint16_t a0v[8], a1v[8];
        a0v[0]=f2bf(af0.x); a0v[1]=f2bf(af0.y); a0v[2]=f2bf(af0.z); a0v[3]=f2bf(af0.w);
        a0v[4]=f2bf(af1.x); a0v[5]=f2bf(af1.y); a0v[6]=f2bf(af1.z); a0v[7]=f2bf(af1.w);
        a1v[0]=f2bf(af2.x); a1v[1]=f2bf(af2.y); a1v[2]=f2bf(af2.z); a1v[3]=f2bf(af2.w);
        a1v[4]=f2bf(af3.x); a1v[5]=f2bf(af3.y); a1v[6]=f2bf(af3.z); a1v[7]=f2bf(af3.w);
        uint4 a0p, a1p;
        __builtin_memcpy(&a0p, a0v, 16);
        __builtin_memcpy(&a1p, a1v, 16);

        __syncthreads();               // previous iter's readers done
        *(uint4*)wA0 = a0p;
        *(uint4*)wA1 = a1p;
        *(uint4*)wB0 = b0;
        *(uint4*)wB1 = b1;
        __syncthreads();               // tile visible

        bf16x8 af[4], bfv[4];
#pragma unroll
        for (int t = 0; t < 4; ++t) {
            af[t]  = *(const bf16x8*)(pA + (size_t)t * 16 * 32);
            bfv[t] = *(const bf16x8*)(pB + (size_t)t * 16 * 32);
        }
#pragma unroll
        for (int mi = 0; mi < 4; ++mi)
#pragma unroll
            for (int ni = 0; ni < 4; ++ni)
                acc[mi][ni] = __builtin_amdgcn_mfma_f32_16x16x32_bf16(
                    af[mi], bfv[ni], acc[mi][ni], 0, 0, 0);
    }

    // epilogue: + bias, exact GELU, fp32 store.
    // C/D layout: col = lane&15, row = quad*4 + reg
#pragma unroll
    for (int ni = 0; ni < 4; ++ni) {
        const int col = n0 + wn * 64 + ni * 16 + r16;
        const float bv = bias[col];
#pragma unroll
        for (int mi = 0; mi < 4; ++mi) {
            const int rowb = m0 + wm * 64 + mi * 16 + quad * 4;
#pragma unroll
            for (int r = 0; r < 4; ++r) {
                float v = acc[mi][ni][r] + bv;
                float g = 0.5f * v * (1.0f + erff(v * 0.70710678118654752f));
                out[(size_t)(rowb + r) * NN + col] = g;
            }
        }
    }
}

extern "C" void kernel_launch(void* const* d_in, const int* in_sizes, int n_in,
                              void* d_out, int out_size, void* d_ws, size_t ws_size,
                              hipStream_t stream) {
    const float* x      = (const float*)d_in[0];   // [B,S,F_IN] fp32
    const float* w      = (const float*)d_in[1];   // [QOUT,QIN,P] fp32
    const float* bias   = (const float*)d_in[2];   // [F_OUT] fp32
    const int* sign_bits = (const int*)d_in[3];    // [F_IN] int32
    float* out = (float*)d_out;                    // [B,S,F_OUT] fp32
    uint16_t* Wt = (uint16_t*)d_ws;                // [N][K] bf16 = 33.5 MB

    // 1) dense circulant weight (bf16) with sign diag folded in
    build_w<<<(NN * 512) / 256, 256, 0, stream>>>(w, sign_bits, Wt);

    // 2) GEMM + bias + GELU
    dim3 grid(NN / 128, MM / 128);
    gemm_bias_gelu<<<grid, 256, 0, stream>>>(x, Wt, bias, out);
}

// Round 3
// 555.393 us; speedup vs baseline: 1.2753x; 1.2753x over previous
//
#include <hip/hip_runtime.h>
#include <hip/hip_bf16.h>
#include <stdint.h>

// Problem constants
#define MM 8192   // B*S
#define NN 4096   // F_OUT
#define KK 4096   // F_IN
#define PP 512
#define QIN 8
#define QOUT 8

typedef __bf16 bf16x8 __attribute__((ext_vector_type(8)));
typedef float  f32x4  __attribute__((ext_vector_type(4)));

static __device__ __forceinline__ uint16_t f2bf(float f) {
    uint32_t x = __builtin_bit_cast(uint32_t, f);
    uint32_t r = (x + 0x7fffu + ((x >> 16) & 1u)) >> 16;  // RNE
    return (uint16_t)r;
}

// async 16B/lane global->LDS (wave-uniform LDS base + lane*16 in HW)
static __device__ __forceinline__ void gld_lds16(const void* g, void* l) {
    __builtin_amdgcn_global_load_lds(
        (const __attribute__((address_space(1))) unsigned int*)g,
        (__attribute__((address_space(3))) unsigned int*)l, 16, 0, 0);
}

// ---------------------------------------------------------------------------
// build_w v2: Wt[n][k] = bf16(w[o][i][(r-j)&511]) ^ sign(k), [N][K] bf16.
// One block per (o, i, 4-n-chunk): stage wrow + sign mask in LDS, then
// 256 threads x 8 consecutive k = 16B coalesced writes.
// ---------------------------------------------------------------------------
__global__ __launch_bounds__(256) void build_w(const float* __restrict__ w,
                                               const int* __restrict__ sign_bits,
                                               uint16_t* __restrict__ Wt) {
    __shared__ uint16_t sw[512];
    __shared__ uint16_t ss[512];
    const int bi = blockIdx.x;
    const int o  = bi >> 10;          // / (QIN*128)
    const int i  = (bi >> 7) & 7;
    const int nc = bi & 127;          // 4-n chunk
    const float* wrow = w + (((size_t)o * QIN + i) << 9);
    const int*   srow = sign_bits + ((size_t)i << 9);
    const int t = threadIdx.x;
    sw[t]       = f2bf(wrow[t]);
    sw[t + 256] = f2bf(wrow[t + 256]);
    ss[t]       = srow[t]       ? 0x8000u : 0u;
    ss[t + 256] = srow[t + 256] ? 0x8000u : 0u;
    __syncthreads();

    const int n_off = t >> 6;         // 0..3
    const int kg    = (t & 63) * 8;   // 0..504
    const int n = (o << 9) + (nc << 2) + n_off;
    const int r = n & 511;
    uint16_t vals[8];
#pragma unroll
    for (int u = 0; u < 8; ++u) {
        int j = kg + u;
        vals[u] = (uint16_t)(sw[(r - j) & 511] ^ ss[j]);
    }
    uint4 pk;
    __builtin_memcpy(&pk, vals, 16);
    *(uint4*)(Wt + (size_t)n * KK + ((size_t)i << 9) + kg) = pk;
}

// ---------------------------------------------------------------------------
// convert_x: fp32 -> bf16, 8 elements/thread.
// ---------------------------------------------------------------------------
__global__ __launch_bounds__(256) void convert_x(const float* __restrict__ x,
                                                 uint16_t* __restrict__ xb) {
    size_t idx = (size_t)blockIdx.x * 256 + threadIdx.x;
    const float4* p = (const float4*)x + idx * 2;
    float4 a = p[0], b = p[1];
    uint16_t v[8] = {f2bf(a.x), f2bf(a.y), f2bf(a.z), f2bf(a.w),
                     f2bf(b.x), f2bf(b.y), f2bf(b.z), f2bf(b.w)};
    uint4 pk;
    __builtin_memcpy(&pk, v, 16);
    *(uint4*)(xb + idx * 8) = pk;
}

// ---------------------------------------------------------------------------
// gemm_m97: C = gelu(Xb @ Wt^T + bias), both operands bf16, staging via
// global_load_lds width-16. 128x128x32, 4 waves (2x2), 4x4 16x16x32 MFMA.
// ---------------------------------------------------------------------------
__global__ __launch_bounds__(256) void gemm_m97(const uint16_t* __restrict__ A,
                                                const uint16_t* __restrict__ Wt,
                                                const float* __restrict__ bias,
                                                float* __restrict__ out) {
    __shared__ uint16_t sA[128 * 32];
    __shared__ uint16_t sB[128 * 32];

    const int tid  = threadIdx.x;
    const int lane = tid & 63;
    const int wave = tid >> 6;
    const int wm   = wave & 1;
    const int wn   = wave >> 1;
    const int quad = lane >> 4;
    const int r16  = lane & 15;

    const int m0 = blockIdx.y * 128;
    const int n0 = blockIdx.x * 128;

    // staging map: thread t -> row t>>2 (and +64), cols (t&3)*8.
    // LDS byte offset = t*16  => lane-linear within each wave. (DMA constraint)
    const int srow = tid >> 2;
    const int scol = (tid & 3) * 8;

    const uint16_t* gA0 = A  + (size_t)(m0 + srow)      * KK + scol;
    const uint16_t* gA1 = A  + (size_t)(m0 + srow + 64) * KK + scol;
    const uint16_t* gB0 = Wt + (size_t)(n0 + srow)      * KK + scol;
    const uint16_t* gB1 = Wt + (size_t)(n0 + srow + 64) * KK + scol;

    // wave-uniform LDS bases (elements): wave covers bytes [w*1024,(w+1)*1024)
    uint16_t* lA0 = sA + wave * 512;
    uint16_t* lA1 = sA + 64 * 32 + wave * 512;
    uint16_t* lB0 = sB + wave * 512;
    uint16_t* lB1 = sB + 64 * 32 + wave * 512;

    const uint16_t* pA = sA + (size_t)(wm * 64 + r16) * 32 + quad * 8;
    const uint16_t* pB = sB + (size_t)(wn * 64 + r16) * 32 + quad * 8;

    f32x4 acc[4][4];
#pragma unroll
    for (int mi = 0; mi < 4; ++mi)
#pragma unroll
        for (int ni = 0; ni < 4; ++ni)
            acc[mi][ni] = (f32x4)(0.0f);

    for (int k0 = 0; k0 < KK; k0 += 32) {
        __syncthreads();               // previous iter's readers done
        gld_lds16(gA0 + k0, lA0);
        gld_lds16(gA1 + k0, lA1);
        gld_lds16(gB0 + k0, lB0);
        gld_lds16(gB1 + k0, lB1);
        __syncthreads();               // drains vmcnt -> tile visible

        bf16x8 af[4], bfv[4];
#pragma unroll
        for (int t = 0; t < 4; ++t) {
            af[t]  = *(const bf16x8*)(pA + (size_t)t * 16 * 32);
            bfv[t] = *(const bf16x8*)(pB + (size_t)t * 16 * 32);
        }
#pragma unroll
        for (int mi = 0; mi < 4; ++mi)
#pragma unroll
            for (int ni = 0; ni < 4; ++ni)
                acc[mi][ni] = __builtin_amdgcn_mfma_f32_16x16x32_bf16(
                    af[mi], bfv[ni], acc[mi][ni], 0, 0, 0);
    }

    // epilogue: C/D layout col = lane&15, row = quad*4 + reg
#pragma unroll
    for (int ni = 0; ni < 4; ++ni) {
        const int col = n0 + wn * 64 + ni * 16 + r16;
        const float bv = bias[col];
#pragma unroll
        for (int mi = 0; mi < 4; ++mi) {
            const int rowb = m0 + wm * 64 + mi * 16 + quad * 4;
#pragma unroll
            for (int r = 0; r < 4; ++r) {
                float v = acc[mi][ni][r] + bv;
                float g = 0.5f * v * (1.0f + erff(v * 0.70710678118654752f));
                out[(size_t)(rowb + r) * NN + col] = g;
            }
        }
    }
}

// ---------------------------------------------------------------------------
// Fallback GEMM (round-2, fp32 A converted in-kernel) for small ws_size.
// ---------------------------------------------------------------------------
__global__ __launch_bounds__(256) void gemm_fb(const float* __restrict__ A,
                                               const uint16_t* __restrict__ Wt,
                                               const float* __restrict__ bias,
                                               float* __restrict__ out) {
    __shared__ uint16_t sA[128 * 32];
    __shared__ uint16_t sB[128 * 32];
    const int tid  = threadIdx.x;
    const int lane = tid & 63;
    const int wave = tid >> 6;
    const int wm   = wave & 1;
    const int wn   = wave >> 1;
    const int quad = lane >> 4;
    const int r16  = lane & 15;
    const int m0 = blockIdx.y * 128;
    const int n0 = blockIdx.x * 128;
    const int srow = tid >> 2;
    const int scol = (tid & 3) * 8;
    const float*    gA0 = A  + (size_t)(m0 + srow)      * KK + scol;
    const float*    gA1 = A  + (size_t)(m0 + srow + 64) * KK + scol;
    const uint16_t* gB0 = Wt + (size_t)(n0 + srow)      * KK + scol;
    const uint16_t* gB1 = Wt + (size_t)(n0 + srow + 64) * KK + scol;
    uint16_t* wA0 = sA + srow * 32 + scol;
    uint16_t* wA1 = sA + (srow + 64) * 32 + scol;
    uint16_t* wB0 = sB + srow * 32 + scol;
    uint16_t* wB1 = sB + (srow + 64) * 32 + scol;
    const uint16_t* pA = sA + (size_t)(wm * 64 + r16) * 32 + quad * 8;
    const uint16_t* pB = sB + (size_t)(wn * 64 + r16) * 32 + quad * 8;
    f32x4 acc[4][4];
#pragma unroll
    for (int mi = 0; mi < 4; ++mi)
#pragma unroll
        for (int ni = 0; ni < 4; ++ni) acc[mi][ni] = (f32x4)(0.0f);
    for (int k0 = 0; k0 < KK; k0 += 32) {
        float4 af0 = *(const float4*)(gA0 + k0);
        float4 af1 = *(const float4*)(gA0 + k0 + 4);
        float4 af2 = *(const float4*)(gA1 + k0);
        float4 af3 = *(const float4*)(gA1 + k0 + 4);
        uint4  b0  = *(const uint4*)(gB0 + k0);
        uint4  b1  = *(const uint4*)(gB1 + k0);
        uint16_t a0v[8], a1v[8];
        a0v[0]=f2bf(af0.x); a0v[1]=f2bf(af0.y); a0v[2]=f2bf(af0.z); a0v[3]=f2bf(af0.w);
        a0v[4]=f2bf(af1.x); a0v[5]=f2bf(af1.y); a0v[6]=f2bf(af1.z); a0v[7]=f2bf(af1.w);
        a1v[0]=f2bf(af2.x); a1v[1]=f2bf(af2.y); a1v[2]=f2bf(af2.z); a1v[3]=f2bf(af2.w);
        a1v[4]=f2bf(af3.x); a1v[5]=f2bf(af3.y); a1v[6]=f2bf(af3.z); a1v[7]=f2bf(af3.w);
        uint4 a0p, a1p;
        __builtin_memcpy(&a0p, a0v, 16);
        __builtin_memcpy(&a1p, a1v, 16);
        __syncthreads();
        *(uint4*)wA0 = a0p; *(uint4*)wA1 = a1p;
        *(uint4*)wB0 = b0;  *(uint4*)wB1 = b1;
        __syncthreads();
        bf16x8 af[4], bfv[4];
#pragma unroll
        for (int t = 0; t < 4; ++t) {
            af[t]  = *(const bf16x8*)(pA + (size_t)t * 16 * 32);
            bfv[t] = *(const bf16x8*)(pB + (size_t)t * 16 * 32);
        }
#pragma unroll
        for (int mi = 0; mi < 4; ++mi)
#pragma unroll
            for (int ni = 0; ni < 4; ++ni)
                acc[mi][ni] = __builtin_amdgcn_mfma_f32_16x16x32_bf16(
                    af[mi], bfv[ni], acc[mi][ni], 0, 0, 0);
    }
#pragma unroll
    for (int ni = 0; ni < 4; ++ni) {
        const int col = n0 + wn * 64 + ni * 16 + r16;
        const float bv = bias[col];
#pragma unroll
        for (int mi = 0; mi < 4; ++mi) {
            const int rowb = m0 + wm * 64 + mi * 16 + quad * 4;
#pragma unroll
            for (int r = 0; r < 4; ++r) {
                float v = acc[mi][ni][r] + bv;
                float g = 0.5f * v * (1.0f + erff(v * 0.70710678118654752f));
                out[(size_t)(rowb + r) * NN + col] = g;
            }
        }
    }
}

extern "C" void kernel_launch(void* const* d_in, const int* in_sizes, int n_in,
                              void* d_out, int out_size, void* d_ws, size_t ws_size,
                              hipStream_t stream) {
    const float* x      = (const float*)d_in[0];
    const float* w      = (const float*)d_in[1];
    const float* bias   = (const float*)d_in[2];
    const int* sign_bits = (const int*)d_in[3];
    float* out = (float*)d_out;

    uint16_t* Wt = (uint16_t*)d_ws;                       // 33,554,432 B
    const size_t WT_BYTES = (size_t)NN * KK * 2;
    const size_t XB_BYTES = (size_t)MM * KK * 2;          // 67,108,864 B

    build_w<<<QOUT * QIN * 128, 256, 0, stream>>>(w, sign_bits, Wt);

    dim3 grid(NN / 128, MM / 128);
    if (ws_size >= WT_BYTES + XB_BYTES) {
        uint16_t* Xb = (uint16_t*)((char*)d_ws + WT_BYTES);
        convert_x<<<(MM * KK) / (8 * 256), 256, 0, stream>>>(x, Xb);
        gemm_m97<<<grid, 256, 0, stream>>>(Xb, Wt, bias, out);
    } else {
        gemm_fb<<<grid, 256, 0, stream>>>(x, Wt, bias, out);
    }
}

// Round 4
// 420.861 us; speedup vs baseline: 1.6830x; 1.3197x over previous
//
#include <hip/hip_runtime.h>
#include <stdint.h>
#include <math.h>

// Problem constants
#define NTOK 8192   // B*S tokens
#define FIN  4096
#define FOUT 4096
#define PP   512
#define QIN  8
#define QOUT 8
#define NFREQ 257   // P/2+1

// ---------------------------------------------------------------------------
// wf_build: Wf[f][o][i] = (1/512) * DFT_512(w[o][i])[f], f in [0,256].
// One block per (o,i); LDS twiddle table; incremental (f*n)&511 indexing.
// ---------------------------------------------------------------------------
__global__ __launch_bounds__(256) void wf_build(const float* __restrict__ w,
                                                float2* __restrict__ Wf) {
    __shared__ float  sw[512];
    __shared__ float2 tb[512];   // tb[k] = (cos(2pi k/512), -sin(2pi k/512))
    const int blk = blockIdx.x;          // o*8 + i
    const float* wrow = w + (size_t)blk * 512;
    const int t = threadIdx.x;
    sw[t]       = wrow[t];
    sw[t + 256] = wrow[t + 256];
    const float th = -6.283185307179586f / 512.0f;
    {
        float a0 = th * (float)t, a1 = th * (float)(t + 256);
        tb[t]       = make_float2(cosf(a0), sinf(a0));
        tb[t + 256] = make_float2(cosf(a1), sinf(a1));
    }
    __syncthreads();

    for (int f = t; f <= 256; f += 256) {   // t==0 also does f=256
        float re = 0.f, im = 0.f;
        int idx = 0;
        for (int n = 0; n < 512; ++n) {
            const float2 e = tb[idx];
            const float  v = sw[n];
            re += v * e.x;
            im += v * e.y;
            idx = (idx + f) & 511;
        }
        Wf[(size_t)f * 64 + blk] = make_float2(re * (1.f / 512.f), im * (1.f / 512.f));
    }
}

// ---------------------------------------------------------------------------
// 9-stage Stockham radix-2 FFT over 512 complex points, one WAVE per FFT.
// s,d are the wave-private 512-entry ping-pong buffers. Same-wave LDS ops are
// processed in order by HW -> no barriers needed between stages.
// Forward: W = e^{-2pi i/512}; inv!=0 conjugates the twiddles.
// Result ends in the second buffer (9 = odd stage count); returned pointer.
// ---------------------------------------------------------------------------
static __device__ __forceinline__ float2* fft9(float2* s, float2* d,
                                               const float2* tw, int lane, int inv) {
    for (int t = 0; t < 9; ++t) {
        const int smask = (1 << t) - 1;
#pragma unroll
        for (int u = 0; u < 4; ++u) {
            const int jb = u * 64 + lane;          // butterfly index 0..255
            const float2 a  = s[jb];
            const float2 b  = s[jb + 256];
            float2 wp = tw[jb & ~smask];
            const float wy = inv ? -wp.y : wp.y;
            const float2 sum = make_float2(a.x + b.x, a.y + b.y);
            const float2 dif = make_float2(a.x - b.x, a.y - b.y);
            const float2 pr  = make_float2(dif.x * wp.x - dif.y * wy,
                                           dif.x * wy + dif.y * wp.x);
            const int widx = ((jb & ~smask) << 1) | (jb & smask);
            d[widx]             = sum;
            d[widx + smask + 1] = pr;              // +s
        }
        float2* tmp = s; s = d; d = tmp;
    }
    return s;   // result buffer
}

// ---------------------------------------------------------------------------
// fft_conv: one block (256 thr, 4 waves) per token.
//   pack:  Z_c[n] = xs[2c*512+n] + i*xs[(2c+1)*512+n], c=0..3  (sign folded)
//   fwd:   wave c FFTs Z_c  (ZA -> ... -> ZB)
//   einsum per f: unpack Xf[i][f] from Z_c via Hermitian split,
//                 Y[o] = sum_i Xf[i]*Wf[f][o][i], build V_c spectra into ZA
//   inv:   wave c inverse-FFTs V_c (ZA -> ... -> ZB), y real pairs
//   epi:   bias + exact GELU, float4 stores
// ---------------------------------------------------------------------------
__global__ __launch_bounds__(256) void fft_conv(const float* __restrict__ x,
                                                const int* __restrict__ sign_bits,
                                                const float2* __restrict__ Wf,
                                                const float* __restrict__ bias,
                                                float* __restrict__ out) {
    __shared__ float2 ZA[2048];
    __shared__ float2 ZB[2048];
    __shared__ float2 tw[256];   // tw[k] = (cos(2pi k/512), -sin(2pi k/512))

    const int tid  = threadIdx.x;
    const int wave = tid >> 6;
    const int lane = tid & 63;
    const float* xin  = x   + (size_t)blockIdx.x * FIN;
    float*       yout = out + (size_t)blockIdx.x * FOUT;

    {
        const float ang = (-6.283185307179586f / 512.0f) * (float)tid;
        tw[tid] = make_float2(cosf(ang), sinf(ang));
    }

    // ---- pack x * sign into ZA as 4 complex sequences ----
#pragma unroll
    for (int it = 0; it < 2; ++it) {
        const int u = it * 1024 + tid * 4;       // 0..2047
        const int c = u >> 9;
        const int n = u & 511;
        const float4 xa = *(const float4*)(xin + c * 1024 + n);
        const float4 xb = *(const float4*)(xin + c * 1024 + 512 + n);
        const int4   sa = *(const int4*)(sign_bits + c * 1024 + n);
        const int4   sb = *(const int4*)(sign_bits + c * 1024 + 512 + n);
        const float va0 = sa.x ? -xa.x : xa.x, va1 = sa.y ? -xa.y : xa.y;
        const float va2 = sa.z ? -xa.z : xa.z, va3 = sa.w ? -xa.w : xa.w;
        const float vb0 = sb.x ? -xb.x : xb.x, vb1 = sb.y ? -xb.y : xb.y;
        const float vb2 = sb.z ? -xb.z : xb.z, vb3 = sb.w ? -xb.w : xb.w;
        float2* dst = &ZA[c * 512 + n];
        dst[0] = make_float2(va0, vb0);
        dst[1] = make_float2(va1, vb1);
        dst[2] = make_float2(va2, vb2);
        dst[3] = make_float2(va3, vb3);
    }
    __syncthreads();

    // ---- forward FFT, one wave per complex sequence ----
    fft9(&ZA[wave * 512], &ZB[wave * 512], tw, lane, 0);   // result in ZB
    __syncthreads();

    // ---- spectral einsum + Hermitian repack into ZA ----
    for (int f = tid; f <= 256; f += 256) {     // thread 0 also handles f=256
        float2 Xf[8];
#pragma unroll
        for (int c = 0; c < 4; ++c) {
            const float2 zp = ZB[c * 512 + f];
            const float2 zm = ZB[c * 512 + ((512 - f) & 511)];
            // A[f] = (Z[f]+conj(Z[-f]))/2 ; B[f] = (Z[f]-conj(Z[-f]))/(2i)
            Xf[2 * c]     = make_float2(0.5f * (zp.x + zm.x), 0.5f * (zp.y - zm.y));
            Xf[2 * c + 1] = make_float2(0.5f * (zp.y + zm.y), -0.5f * (zp.x - zm.x));
        }
        const float2* wf = Wf + (size_t)f * 64;   // [o][i]
        float2 Y[8];
#pragma unroll
        for (int o = 0; o < 8; ++o) {
            float re = 0.f, im = 0.f;
#pragma unroll
            for (int i = 0; i < 8; ++i) {
                const float2 xv = Xf[i];
                const float2 wv = wf[o * 8 + i];
                re += xv.x * wv.x - xv.y * wv.y;
                im += xv.x * wv.y + xv.y * wv.x;
            }
            Y[o] = make_float2(re, im);
        }
        // V_c[f] = Y[2c] + i*Y[2c+1]; V_c[512-f] = conj(Y[2c]) + i*conj(Y[2c+1])
#pragma unroll
        for (int c = 0; c < 4; ++c) {
            const float2 y0 = Y[2 * c], y1 = Y[2 * c + 1];
            ZA[c * 512 + f] = make_float2(y0.x - y1.y, y0.y + y1.x);
            if (f != 0 && f != 256)
                ZA[c * 512 + 512 - f] = make_float2(y0.x + y1.y, y1.x - y0.y);
        }
    }
    __syncthreads();

    // ---- inverse FFT (conj twiddles; 1/512 folded into Wf) ----
    fft9(&ZA[wave * 512], &ZB[wave * 512], tw, lane, 1);   // result in ZB
    __syncthreads();

    // ---- epilogue: v_c[n] = y[2c*512+n] + i*y[(2c+1)*512+n] ----
#pragma unroll
    for (int it = 0; it < 4; ++it) {
        const int k = it * 1024 + tid * 4;       // 0..4095
        const int o = k >> 9;
        const int c = o >> 1;
        const int comp = o & 1;
        const int n = k & 511;
        const float2* z = &ZB[c * 512 + n];
        const float4 bv = *(const float4*)(bias + k);
        float v0 = (comp ? z[0].y : z[0].x) + bv.x;
        float v1 = (comp ? z[1].y : z[1].x) + bv.y;
        float v2 = (comp ? z[2].y : z[2].x) + bv.z;
        float v3 = (comp ? z[3].y : z[3].x) + bv.w;
        float4 g;
        g.x = 0.5f * v0 * (1.0f + erff(v0 * 0.70710678118654752f));
        g.y = 0.5f * v1 * (1.0f + erff(v1 * 0.70710678118654752f));
        g.z = 0.5f * v2 * (1.0f + erff(v2 * 0.70710678118654752f));
        g.w = 0.5f * v3 * (1.0f + erff(v3 * 0.70710678118654752f));
        *(float4*)(yout + k) = g;
    }
}

extern "C" void kernel_launch(void* const* d_in, const int* in_sizes, int n_in,
                              void* d_out, int out_size, void* d_ws, size_t ws_size,
                              hipStream_t stream) {
    const float* x       = (const float*)d_in[0];   // [B,S,F_IN] fp32
    const float* w       = (const float*)d_in[1];   // [QOUT,QIN,P] fp32
    const float* bias    = (const float*)d_in[2];   // [F_OUT] fp32
    const int*  sign_bits = (const int*)d_in[3];    // [F_IN] int32
    float* out = (float*)d_out;                     // [B,S,F_OUT] fp32

    float2* Wf = (float2*)d_ws;                     // [257][8][8] complex = 131.6 KB

    wf_build<<<QOUT * QIN, 256, 0, stream>>>(w, Wf);
    fft_conv<<<NTOK, 256, 0, stream>>>(x, sign_bits, Wf, bias, out);
}